// Round 1
// baseline (100.983 us; speedup 1.0000x reference)
//
#include <hip/hip_runtime.h>
#include <hip/hip_bf16.h>

// SE_loss: BCE(se_pred[64,6], class-presence(target[64,512,512])) -> scalar mean.
// Memory-bound: 67.1 MB int32 read of target; everything else is negligible.

#define NCLASS 6
#define NBATCH 64
#define PER_BATCH (512 * 512)       // ints per batch image
#define BLOCKS_PER_BATCH 32
#define THREADS 256

// Step 2: per-batch class-presence bitmask via OR-reduction.
// Grid: NBATCH * BLOCKS_PER_BATCH blocks; each batch's 32 blocks x 256 threads
// cover 65536 int4 vectors (8 per thread), fully coalesced 16B/lane.
__global__ __launch_bounds__(THREADS) void presence_kernel(
    const int* __restrict__ target, unsigned* __restrict__ masks) {
    const int batch = blockIdx.x / BLOCKS_PER_BATCH;
    const int sub   = blockIdx.x % BLOCKS_PER_BATCH;

    const int4* __restrict__ p =
        (const int4*)(target + (size_t)batch * PER_BATCH);
    const int nvec     = PER_BATCH / 4;                 // 65536 int4 per batch
    const int nthreads = BLOCKS_PER_BATCH * THREADS;    // 8192 threads per batch
    int idx = sub * THREADS + (int)threadIdx.x;         // 0..8191

    unsigned m = 0u;
#pragma unroll
    for (int i = 0; i < nvec / nthreads; ++i) {         // 8 iterations
        int4 v = p[idx + i * nthreads];
        m |= (1u << v.x) | (1u << v.y) | (1u << v.z) | (1u << v.w);
    }

    // Wave-64 OR reduction
#pragma unroll
    for (int off = 32; off > 0; off >>= 1)
        m |= (unsigned)__shfl_down((int)m, off, 64);

    __shared__ unsigned sm;
    if (threadIdx.x == 0) sm = 0u;
    __syncthreads();
    if ((threadIdx.x & 63) == 0) atomicOr(&sm, m);
    __syncthreads();
    if (threadIdx.x == 0) atomicOr(&masks[batch], sm);
}

// Step 3: BCE epilogue over 64*6 = 384 terms, single block.
__global__ __launch_bounds__(384) void bce_kernel(
    const float* __restrict__ se_pred, const unsigned* __restrict__ masks,
    float* __restrict__ out) {
    const int i = (int)threadIdx.x;          // 0..383  == b*NCLASS + c
    const int b = i / NCLASS;
    const int c = i % NCLASS;

    const float p = se_pred[i];
    const float t = ((masks[b] >> c) & 1u) ? 1.0f : 0.0f;
    // torch BCELoss clamps log outputs at -100
    const float lp  = fmaxf(logf(p), -100.0f);
    const float l1p = fmaxf(log1pf(-p), -100.0f);
    float term = -(t * lp + (1.0f - t) * l1p);

    // Reduce within each wave (6 waves), then across waves in LDS.
#pragma unroll
    for (int off = 32; off > 0; off >>= 1)
        term += __shfl_down(term, off, 64);

    __shared__ float partial[6];
    if ((threadIdx.x & 63) == 0) partial[threadIdx.x >> 6] = term;
    __syncthreads();
    if (threadIdx.x == 0) {
        float s = 0.0f;
#pragma unroll
        for (int w = 0; w < 6; ++w) s += partial[w];
        out[0] = s * (1.0f / (NBATCH * NCLASS));
    }
}

extern "C" void kernel_launch(void* const* d_in, const int* in_sizes, int n_in,
                              void* d_out, int out_size, void* d_ws, size_t ws_size,
                              hipStream_t stream) {
    const float* se_pred = (const float*)d_in[0];   // [64,6] fp32
    const int*   target  = (const int*)d_in[1];     // [64,512,512] int32
    float*       out     = (float*)d_out;           // scalar fp32
    unsigned*    masks   = (unsigned*)d_ws;         // 64 presence bitmasks

    // d_ws is re-poisoned to 0xAA before every launch — zero the masks.
    hipMemsetAsync(masks, 0, NBATCH * sizeof(unsigned), stream);

    presence_kernel<<<NBATCH * BLOCKS_PER_BATCH, THREADS, 0, stream>>>(target, masks);
    bce_kernel<<<1, 384, 0, stream>>>(se_pred, masks, out);
}

// Round 2
// 90.754 us; speedup vs baseline: 1.1127x; 1.1127x over previous
//
#include <hip/hip_runtime.h>
#include <hip/hip_bf16.h>

// SE_loss: BCE(se_pred[64,6], class-presence(target[64,512,512] int32)) -> scalar.
//
// Key insight: presence mask is a monotone OR toward 0x3F (all 6 classes).
// Once a batch's mask == 0x3F nothing later can change it, so early-exit is
// EXACT for all inputs. With uniform random labels, one 16 KB chunk/batch
// almost surely contains all 6 classes -> ~1 MB read instead of 67 MB.
// Worst case (a class truly absent) still scans the full batch.

#define NCLASS 6
#define NBATCH 64
#define PER_BATCH (512 * 512)       // int32 elements per batch image
#define PK_THREADS 1024             // 16 waves

// One block per batch. Each iteration: 1024 threads x int4 = 16 KB coalesced,
// wave OR-reduce, one LDS atomicOr per wave, barrier, early-exit check.
__global__ __launch_bounds__(PK_THREADS) void presence_kernel(
    const int* __restrict__ target, unsigned* __restrict__ masks) {
    const int batch = blockIdx.x;
    const int4* __restrict__ p =
        (const int4*)(target + (size_t)batch * PER_BATCH);

    __shared__ unsigned sm;
    if (threadIdx.x == 0) sm = 0u;
    __syncthreads();

    const int NV = PER_BATCH / 4;   // 65536 int4 vectors per batch
    for (int base = 0; base < NV; base += PK_THREADS) {   // up to 64 iters
        int4 v = p[base + (int)threadIdx.x];
        unsigned m = (1u << v.x) | (1u << v.y) | (1u << v.z) | (1u << v.w);

        // Wave-64 OR reduction
#pragma unroll
        for (int off = 32; off > 0; off >>= 1)
            m |= (unsigned)__shfl_down((int)m, off, 64);

        if ((threadIdx.x & 63) == 0) atomicOr(&sm, m);
        __syncthreads();
        // sm is uniform here (all atomicOrs precede the barrier) -> uniform break.
        if (sm == 0x3Fu) break;
        __syncthreads();   // protect sm re-read ordering across iterations
    }

    __syncthreads();
    if (threadIdx.x == 0) masks[batch] = sm;
}

// BCE epilogue over 64*6 = 384 terms, single block.
__global__ __launch_bounds__(384) void bce_kernel(
    const float* __restrict__ se_pred, const unsigned* __restrict__ masks,
    float* __restrict__ out) {
    const int i = (int)threadIdx.x;          // 0..383  == b*NCLASS + c
    const int b = i / NCLASS;
    const int c = i % NCLASS;

    const float p = se_pred[i];
    const float t = ((masks[b] >> c) & 1u) ? 1.0f : 0.0f;
    // torch BCELoss clamps log outputs at -100
    const float lp  = fmaxf(logf(p), -100.0f);
    const float l1p = fmaxf(log1pf(-p), -100.0f);
    float term = -(t * lp + (1.0f - t) * l1p);

    // Reduce within each wave (6 waves), then across waves in LDS.
#pragma unroll
    for (int off = 32; off > 0; off >>= 1)
        term += __shfl_down(term, off, 64);

    __shared__ float partial[6];
    if ((threadIdx.x & 63) == 0) partial[threadIdx.x >> 6] = term;
    __syncthreads();
    if (threadIdx.x == 0) {
        float s = 0.0f;
#pragma unroll
        for (int w = 0; w < 6; ++w) s += partial[w];
        out[0] = s * (1.0f / (NBATCH * NCLASS));
    }
}

extern "C" void kernel_launch(void* const* d_in, const int* in_sizes, int n_in,
                              void* d_out, int out_size, void* d_ws, size_t ws_size,
                              hipStream_t stream) {
    const float* se_pred = (const float*)d_in[0];   // [64,6] fp32
    const int*   target  = (const int*)d_in[1];     // [64,512,512] int32
    float*       out     = (float*)d_out;           // scalar fp32
    unsigned*    masks   = (unsigned*)d_ws;         // 64 presence bitmasks

    // masks are plain-stored (not accumulated) -> no zero-init dispatch needed.
    presence_kernel<<<NBATCH, PK_THREADS, 0, stream>>>(target, masks);
    bce_kernel<<<1, 384, 0, stream>>>(se_pred, masks, out);
}